// Round 1
// baseline (30.934 us; speedup 1.0000x reference)
//
#include <hip/hip_runtime.h>

#define BB 512
#define HH 8
#define CC 8192
// torch BCE clamps log at -100
#define LOG_CLAMP -100.0f

// Kernel 1: w[c] = sum_h lam[h] * La[h, c]
__global__ void weight_kernel(const float* __restrict__ La,
                              const float* __restrict__ lam,
                              float* __restrict__ w) {
    int c = blockIdx.x * blockDim.x + threadIdx.x;
    if (c < CC) {
        float acc = 0.0f;
#pragma unroll
        for (int h = 0; h < HH; ++h) {
            acc += lam[h] * La[h * CC + c];
        }
        w[c] = acc;
    }
}

__device__ __forceinline__ float bce_elem(float p, float t) {
    // -( t * max(log(p), -100) + (1-t) * max(log1p(-p), -100) )
    float lp   = fmaxf(logf(p), LOG_CLAMP);      // fmaxf(-inf,-100) = -100
    float l1mp = fmaxf(log1pf(-p), LOG_CLAMP);
    return -(t * lp + (1.0f - t) * l1mp);
}

// Kernel 2: out += (1/C) * sum_{b,c} w[c] * bce_elem(y_pred[b,c], y_true[b,c])
__global__ void bce_reduce_kernel(const float* __restrict__ y_pred,
                                  const float* __restrict__ y_true,
                                  const float* __restrict__ w,
                                  float* __restrict__ out) {
    const int nvec = (BB * CC) / 4;       // 1,048,576 float4 elements
    const int cvec = CC / 4;              // 2048 (power of 2)
    const float4* yp4 = reinterpret_cast<const float4*>(y_pred);
    const float4* yt4 = reinterpret_cast<const float4*>(y_true);
    const float4* w4  = reinterpret_cast<const float4*>(w);

    float acc = 0.0f;
    for (int i = blockIdx.x * blockDim.x + threadIdx.x; i < nvec;
         i += gridDim.x * blockDim.x) {
        float4 p  = yp4[i];
        float4 t  = yt4[i];
        float4 wv = w4[i & (cvec - 1)];
        acc += wv.x * bce_elem(p.x, t.x);
        acc += wv.y * bce_elem(p.y, t.y);
        acc += wv.z * bce_elem(p.z, t.z);
        acc += wv.w * bce_elem(p.w, t.w);
    }

    // wave (64-lane) reduction
#pragma unroll
    for (int off = 32; off > 0; off >>= 1) {
        acc += __shfl_down(acc, off, 64);
    }

    __shared__ float s[4];                // 256 threads = 4 waves
    int wid  = threadIdx.x >> 6;
    int lane = threadIdx.x & 63;
    if (lane == 0) s[wid] = acc;
    __syncthreads();
    if (threadIdx.x == 0) {
        float tot = (s[0] + s[1]) + (s[2] + s[3]);
        atomicAdd(out, tot * (1.0f / (float)CC));
    }
}

extern "C" void kernel_launch(void* const* d_in, const int* in_sizes, int n_in,
                              void* d_out, int out_size, void* d_ws, size_t ws_size,
                              hipStream_t stream) {
    const float* y_pred = (const float*)d_in[0];  // [B, C]
    const float* y_true = (const float*)d_in[1];  // [B, C]
    const float* La     = (const float*)d_in[2];  // [H, C]
    const float* lam    = (const float*)d_in[3];  // [H]
    float* out = (float*)d_out;                   // scalar
    float* w   = (float*)d_ws;                    // C floats of scratch

    hipMemsetAsync(out, 0, sizeof(float), stream);

    weight_kernel<<<CC / 256, 256, 0, stream>>>(La, lam, w);

    bce_reduce_kernel<<<1024, 256, 0, stream>>>(y_pred, y_true, w, out);
}

// Round 2
// 13.154 us; speedup vs baseline: 2.3517x; 2.3517x over previous
//
#include <hip/hip_runtime.h>

#define BB 512
#define HH 8
#define CC 8192
// torch BCE clamps log at -100
#define LOG_CLAMP -100.0f

#define G1 1024   // blocks, main kernel
#define T1 256    // threads, main kernel

__device__ __forceinline__ float bce_elem(float p, float t) {
    // -( t * max(log(p), -100) + (1-t) * max(log(1-p), -100) )
    // p in [0,1): __logf(0) = -inf, fmaxf(-inf,-100) = -100 (torch clamp)
    float lp   = fmaxf(__logf(p), LOG_CLAMP);
    float l1mp = fmaxf(__logf(1.0f - p), LOG_CLAMP);
    return -(t * lp + (1.0f - t) * l1mp);
}

// Fused: per-thread w4 = sum_h lam[h]*La4[h][j] (column group is invariant
// across the grid-stride loop since G1*T1 is a multiple of CC/4), then
// weighted BCE partial reduction. Block partial -> ws[bid] (plain store).
__global__ __launch_bounds__(T1) void fused_bce_kernel(
        const float* __restrict__ y_pred,
        const float* __restrict__ y_true,
        const float* __restrict__ La,
        const float* __restrict__ lam,
        float* __restrict__ partials) {
    const int nvec = (BB * CC) / 4;   // 1,048,576
    const int cvec = CC / 4;          // 2048 (power of 2)

    const int tid0 = blockIdx.x * T1 + threadIdx.x;
    const int j = tid0 & (cvec - 1);  // this thread's column group, fixed

    // per-thread layer weight for its 4 columns
    const float4* La4 = reinterpret_cast<const float4*>(La);
    float4 wv = make_float4(0.f, 0.f, 0.f, 0.f);
#pragma unroll
    for (int h = 0; h < HH; ++h) {
        float l = lam[h];             // uniform -> scalar load
        float4 a = La4[h * cvec + j];
        wv.x += l * a.x;
        wv.y += l * a.y;
        wv.z += l * a.z;
        wv.w += l * a.w;
    }

    const float4* yp4 = reinterpret_cast<const float4*>(y_pred);
    const float4* yt4 = reinterpret_cast<const float4*>(y_true);

    float acc = 0.0f;
    for (int i = tid0; i < nvec; i += G1 * T1) {   // exactly 4 iterations
        float4 p = yp4[i];
        float4 t = yt4[i];
        acc += wv.x * bce_elem(p.x, t.x);
        acc += wv.y * bce_elem(p.y, t.y);
        acc += wv.z * bce_elem(p.z, t.z);
        acc += wv.w * bce_elem(p.w, t.w);
    }

    // wave (64-lane) reduction
#pragma unroll
    for (int off = 32; off > 0; off >>= 1) {
        acc += __shfl_down(acc, off, 64);
    }

    __shared__ float s[T1 / 64];      // 4 waves
    const int wid  = threadIdx.x >> 6;
    const int lane = threadIdx.x & 63;
    if (lane == 0) s[wid] = acc;
    __syncthreads();
    if (threadIdx.x == 0) {
        partials[blockIdx.x] = (s[0] + s[1]) + (s[2] + s[3]);
    }
}

// Finisher: one block sums the G1 partials, plain store (no init needed).
__global__ __launch_bounds__(256) void final_reduce_kernel(
        const float* __restrict__ partials,
        float* __restrict__ out) {
    const float4* p4 = reinterpret_cast<const float4*>(partials);
    float4 v = p4[threadIdx.x];       // 256 threads x float4 = 1024 partials
    float acc = (v.x + v.y) + (v.z + v.w);
#pragma unroll
    for (int off = 32; off > 0; off >>= 1) {
        acc += __shfl_down(acc, off, 64);
    }
    __shared__ float s[4];
    const int wid  = threadIdx.x >> 6;
    const int lane = threadIdx.x & 63;
    if (lane == 0) s[wid] = acc;
    __syncthreads();
    if (threadIdx.x == 0) {
        out[0] = ((s[0] + s[1]) + (s[2] + s[3])) * (1.0f / (float)CC);
    }
}

extern "C" void kernel_launch(void* const* d_in, const int* in_sizes, int n_in,
                              void* d_out, int out_size, void* d_ws, size_t ws_size,
                              hipStream_t stream) {
    const float* y_pred = (const float*)d_in[0];  // [B, C]
    const float* y_true = (const float*)d_in[1];  // [B, C]
    const float* La     = (const float*)d_in[2];  // [H, C]
    const float* lam    = (const float*)d_in[3];  // [H]
    float* out      = (float*)d_out;              // scalar
    float* partials = (float*)d_ws;               // G1 floats of scratch

    fused_bce_kernel<<<G1, T1, 0, stream>>>(y_pred, y_true, La, lam, partials);
    final_reduce_kernel<<<1, 256, 0, stream>>>(partials, out);
}

// Round 3
// 11.452 us; speedup vs baseline: 2.7011x; 1.1486x over previous
//
#include <hip/hip_runtime.h>

#define BB 512
#define HH 8
#define CC 8192
// torch BCE clamps log at -100
#define LOG_CLAMP -100.0f

#define G1 512    // blocks, main kernel
#define T1 256    // threads, main kernel
// G1*T1 = 131072 threads; nvec/(G1*T1) = 8 rows per thread, same column group

__global__ __launch_bounds__(T1) void fused_bce_kernel(
        const float* __restrict__ y_pred,
        const float* __restrict__ y_true,
        const float* __restrict__ La,
        const float* __restrict__ lam,
        float* __restrict__ partials) {
    const int nvec = (BB * CC) / 4;   // 1,048,576
    const int cvec = CC / 4;          // 2048 (power of 2)

    const int tid0 = blockIdx.x * T1 + threadIdx.x;
    const int j = tid0 & (cvec - 1);  // this thread's column group (fixed:
                                      // G1*T1 is a multiple of cvec)

    // per-thread layer weight for its 4 columns: w = sum_h lam[h]*La[h]
    const float4* La4 = reinterpret_cast<const float4*>(La);
    float4 wv = make_float4(0.f, 0.f, 0.f, 0.f);
#pragma unroll
    for (int h = 0; h < HH; ++h) {
        float l = lam[h];             // wave-uniform scalar load
        float4 a = La4[h * cvec + j];
        wv.x += l * a.x;
        wv.y += l * a.y;
        wv.z += l * a.z;
        wv.w += l * a.w;
    }

    const float4* yp4 = reinterpret_cast<const float4*>(y_pred);
    const float4* yt4 = reinterpret_cast<const float4*>(y_true);

    // t is exactly 0.0 or 1.0, so
    //   bce = -( t*max(log p,-100) + (1-t)*max(log(1-p),-100) )
    //       = -max(log(t ? p : 1-p), -100)        (bit-exact, one log)
    float acc = 0.0f;
#pragma unroll
    for (int k = 0; k < 8; ++k) {     // 8 rows per thread
        int i = tid0 + k * (G1 * T1);
        float4 p = yp4[i];
        float4 t = yt4[i];
        float qx = (t.x != 0.0f) ? p.x : (1.0f - p.x);
        float qy = (t.y != 0.0f) ? p.y : (1.0f - p.y);
        float qz = (t.z != 0.0f) ? p.z : (1.0f - p.z);
        float qw = (t.w != 0.0f) ? p.w : (1.0f - p.w);
        acc = fmaf(wv.x, fmaxf(__logf(qx), LOG_CLAMP), acc);
        acc = fmaf(wv.y, fmaxf(__logf(qy), LOG_CLAMP), acc);
        acc = fmaf(wv.z, fmaxf(__logf(qz), LOG_CLAMP), acc);
        acc = fmaf(wv.w, fmaxf(__logf(qw), LOG_CLAMP), acc);
    }

    // wave (64-lane) reduction
#pragma unroll
    for (int off = 32; off > 0; off >>= 1) {
        acc += __shfl_down(acc, off, 64);
    }

    __shared__ float s[T1 / 64];      // 4 waves
    const int wid  = threadIdx.x >> 6;
    const int lane = threadIdx.x & 63;
    if (lane == 0) s[wid] = acc;
    __syncthreads();
    if (threadIdx.x == 0) {
        partials[blockIdx.x] = (s[0] + s[1]) + (s[2] + s[3]);
    }
}

// Finisher: one block of 128 threads sums the G1=512 partials (float4 each),
// plain store (no init dependency anywhere).
__global__ __launch_bounds__(128) void final_reduce_kernel(
        const float* __restrict__ partials,
        float* __restrict__ out) {
    const float4* p4 = reinterpret_cast<const float4*>(partials);
    float4 v = p4[threadIdx.x];       // 128 threads x float4 = 512 partials
    float acc = (v.x + v.y) + (v.z + v.w);
#pragma unroll
    for (int off = 32; off > 0; off >>= 1) {
        acc += __shfl_down(acc, off, 64);
    }
    __shared__ float s[2];
    const int wid  = threadIdx.x >> 6;
    const int lane = threadIdx.x & 63;
    if (lane == 0) s[wid] = acc;
    __syncthreads();
    if (threadIdx.x == 0) {
        out[0] = -(s[0] + s[1]) * (1.0f / (float)CC);
    }
}

extern "C" void kernel_launch(void* const* d_in, const int* in_sizes, int n_in,
                              void* d_out, int out_size, void* d_ws, size_t ws_size,
                              hipStream_t stream) {
    const float* y_pred = (const float*)d_in[0];  // [B, C]
    const float* y_true = (const float*)d_in[1];  // [B, C]
    const float* La     = (const float*)d_in[2];  // [H, C]
    const float* lam    = (const float*)d_in[3];  // [H]
    float* out      = (float*)d_out;              // scalar
    float* partials = (float*)d_ws;               // G1 floats of scratch

    fused_bce_kernel<<<G1, T1, 0, stream>>>(y_pred, y_true, La, lam, partials);
    final_reduce_kernel<<<1, 128, 0, stream>>>(partials, out);
}